// Round 8
// baseline (280.264 us; speedup 1.0000x reference)
//
#include <hip/hip_runtime.h>
#include <math.h>

typedef float  f32x4  __attribute__((ext_vector_type(4)));
typedef int    i32x4  __attribute__((ext_vector_type(4)));
typedef int    i32x16 __attribute__((ext_vector_type(16)));

#define H      4096
#define E      64
#define TOPK   8
#define TILE_T 32

// W -> 5 balanced i8 limbs of round(w*2^41), stored in MFMA-B-fragment order:
// Wb[((m*2+e2)*5 + j)*1024 + lane*16 + slot], lane=(h<<5)|(e&31), k=32m+16h+slot
__global__ __launch_bounds__(256)
void prep_w(const float* __restrict__ Wg, signed char* __restrict__ Wb)
{
  int n = blockIdx.x * 256 + threadIdx.x;   // 16384 = e(64) x m(128) x h(2)
  int h = n & 1, m = (n >> 1) & 127, e = n >> 8;
  const float* wp = Wg + e * 4096 + m * 32 + h * 16;
  signed char lb[5][16];
  #pragma unroll
  for (int s = 0; s < 16; ++s) {
    long long v = (long long)rint((double)wp[s] * 2199023255552.0); // 2^41
    #pragma unroll
    for (int j = 0; j < 4; ++j) {
      signed char b = (signed char)(v & 0xff);
      lb[j][s] = b;
      v = (v - b) >> 8;
    }
    lb[4][s] = (signed char)v;
  }
  int lanei = (h << 5) | (e & 31);
  int e2 = e >> 5;
  #pragma unroll
  for (int j = 0; j < 5; ++j) {
    i32x4 d;
    #pragma unroll
    for (int r = 0; r < 4; ++r)
      d[r] = (lb[j][4*r] & 0xFF) | ((lb[j][4*r+1] & 0xFF) << 8)
           | ((lb[j][4*r+2] & 0xFF) << 16) | ((lb[j][4*r+3] & 0xFF) << 24);
    *(i32x4*)(Wb + (((size_t)(m * 2 + e2) * 5 + j) << 10) + lanei * 16) = d;
  }
}

// comp[kh][e] = C0 * sum_{k in K-quarter kh} round(w[e][k]*2^41),  C0 = 8421504
__global__ __launch_bounds__(256)
void comp_w(const float* __restrict__ Wg, double* __restrict__ compT)
{
  int t = threadIdx.x;           // 256 = kh(4) x e(64)
  int kh = t >> 6, e = t & 63;
  double s = 0.0;
  for (int k = kh * 1024; k < kh * 1024 + 1024; ++k)
    s += rint((double)Wg[e * 4096 + k] * 2199023255552.0);
  compT[kh * 64 + e] = 8421504.0 * s;
}

// Router on the i8 matrix pipe. x ~ trunc(x*2^28) as 4 biased-byte pseudo-limbs
// ((v+2^31)^0x80808080 trick; constant C0 compensation in compT). w = 5 balanced
// limbs of round(w*2^41). 14 limb-pair MFMAs (i+j>=3), exact i32 accumulation,
// f64 combine at scales 2^(8s)-69. C/D readout runtime-probed (R4-proven method).
__global__ __launch_bounds__(512, 2)
void moe_gate_i8(const float* __restrict__ X, const signed char* __restrict__ Wb,
                 const double* __restrict__ compT, float* __restrict__ out,
                 int n_tokens)
{
  __shared__ char sm[65536];   // 4 kh-quarters x 4 limbs x 32 tok x 128B (Ls aliased after)
  double* Ls = (double*)sm;    // [32][64] f64 logits, used after main loop

  const int tid  = threadIdx.x;
  const int lane = tid & 63;
  const int w    = tid >> 6;     // 0..7
  const int kh   = w >> 1;       // K quarter 0..3
  const int e2   = w & 1;        // expert half
  const int t0   = blockIdx.x * TILE_T;
  const int l31  = lane & 31;
  const int h    = lane >> 5;

  // ---- probe (lane,reg)->(row,col) readout of mfma_i32_32x32x32_i8 ----
  i32x16 z;
  #pragma unroll
  for (int r = 0; r < 16; ++r) z[r] = 0;
  int lab = l31 * 0x01010101;
  i32x4 onev = {0x01010101, 0x01010101, 0x01010101, 0x01010101};
  i32x4 labv = {lab, lab, lab, lab};
  i32x16 pr = __builtin_amdgcn_mfma_i32_32x32x32_i8(labv, onev, z, 0, 0, 0);
  i32x16 pc = __builtin_amdgcn_mfma_i32_32x32x32_i8(onev, labv, z, 0, 0, 0);
  int qrow[16], qcol[16];
  #pragma unroll
  for (int r = 0; r < 16; ++r) { qrow[r] = pr[r] >> 5; qcol[r] = pc[r] >> 5; }

  // ---- accumulators per scale class s = i+j in {3..7} ----
  i32x16 acc3 = z, acc4 = z, acc5 = z, acc6 = z, acc7 = z;

  // conversion mapping: pair threads pt over (tok, 32k-segment)
  const int pt = tid & 127;
  const int ctok  = pt >> 2;
  const int ckseg = (pt & 3) * 32;
  const float* xsrc = X + (size_t)(t0 + ctok) * H + kh * 1024 + ckseg;
  char* lbase = sm + kh * 16384;
  const int swzC = (ctok & 7) << 4;
  const int swz  = (l31 & 7) << 4;

  f32x4 xr[8];
  #pragma unroll
  for (int q = 0; q < 8; ++q) xr[q] = *(const f32x4*)(xsrc + q * 4);

  for (int c = 0; c < 8; ++c) {
    // convert chunk c (32 f32 -> 4 limb-planes in LDS)
    #pragma unroll
    for (int qp = 0; qp < 4; ++qp) {
      unsigned w32[2][4];
      #pragma unroll
      for (int hf = 0; hf < 2; ++hf) {
        f32x4 xv = xr[qp * 2 + hf];
        #pragma unroll
        for (int j = 0; j < 4; ++j)
          w32[hf][j] = ((unsigned)(int)(xv[j] * 268435456.0f)) ^ 0x00808080u;
      }
      #pragma unroll
      for (int i = 0; i < 4; ++i) {
        unsigned lo = ((w32[0][0] >> (8*i)) & 0xFF)
                    | (((w32[0][1] >> (8*i)) & 0xFF) << 8)
                    | (((w32[0][2] >> (8*i)) & 0xFF) << 16)
                    | (((w32[0][3] >> (8*i)) & 0xFF) << 24);
        unsigned hi = ((w32[1][0] >> (8*i)) & 0xFF)
                    | (((w32[1][1] >> (8*i)) & 0xFF) << 8)
                    | (((w32[1][2] >> (8*i)) & 0xFF) << 16)
                    | (((w32[1][3] >> (8*i)) & 0xFF) << 24);
        unsigned long long dd = (unsigned long long)lo | ((unsigned long long)hi << 32);
        *(unsigned long long*)(lbase + i * 4096 + ctok * 128 + ((ckseg + 8 * qp) ^ swzC)) = dd;
      }
    }
    // prefetch next chunk (in flight across the consume phase)
    if (c < 7) {
      #pragma unroll
      for (int q = 0; q < 8; ++q)
        xr[q] = *(const f32x4*)(xsrc + (c + 1) * 128 + q * 4);
    }
    __syncthreads();

    // consume: 4 k-steps x 14 MFMAs
    #pragma unroll
    for (int t = 0; t < 4; ++t) {
      const int koff = (t * 32 + h * 16) ^ swz;
      i32x4 a0 = *(const i32x4*)(lbase + 0 * 4096 + l31 * 128 + koff);
      i32x4 a1 = *(const i32x4*)(lbase + 1 * 4096 + l31 * 128 + koff);
      i32x4 a2 = *(const i32x4*)(lbase + 2 * 4096 + l31 * 128 + koff);
      i32x4 a3 = *(const i32x4*)(lbase + 3 * 4096 + l31 * 128 + koff);
      const signed char* wp = Wb + (((size_t)((kh * 32 + c * 4 + t) * 2 + e2) * 5) << 10) + lane * 16;
      i32x4 b0 = *(const i32x4*)(wp);
      i32x4 b1 = *(const i32x4*)(wp + 1024);
      i32x4 b2 = *(const i32x4*)(wp + 2048);
      i32x4 b3 = *(const i32x4*)(wp + 3072);
      i32x4 b4 = *(const i32x4*)(wp + 4096);
      acc3 = __builtin_amdgcn_mfma_i32_32x32x32_i8(a0, b3, acc3, 0, 0, 0);
      acc3 = __builtin_amdgcn_mfma_i32_32x32x32_i8(a1, b2, acc3, 0, 0, 0);
      acc3 = __builtin_amdgcn_mfma_i32_32x32x32_i8(a2, b1, acc3, 0, 0, 0);
      acc3 = __builtin_amdgcn_mfma_i32_32x32x32_i8(a3, b0, acc3, 0, 0, 0);
      acc4 = __builtin_amdgcn_mfma_i32_32x32x32_i8(a0, b4, acc4, 0, 0, 0);
      acc4 = __builtin_amdgcn_mfma_i32_32x32x32_i8(a1, b3, acc4, 0, 0, 0);
      acc4 = __builtin_amdgcn_mfma_i32_32x32x32_i8(a2, b2, acc4, 0, 0, 0);
      acc4 = __builtin_amdgcn_mfma_i32_32x32x32_i8(a3, b1, acc4, 0, 0, 0);
      acc5 = __builtin_amdgcn_mfma_i32_32x32x32_i8(a1, b4, acc5, 0, 0, 0);
      acc5 = __builtin_amdgcn_mfma_i32_32x32x32_i8(a2, b3, acc5, 0, 0, 0);
      acc5 = __builtin_amdgcn_mfma_i32_32x32x32_i8(a3, b2, acc5, 0, 0, 0);
      acc6 = __builtin_amdgcn_mfma_i32_32x32x32_i8(a2, b4, acc6, 0, 0, 0);
      acc6 = __builtin_amdgcn_mfma_i32_32x32x32_i8(a3, b3, acc6, 0, 0, 0);
      acc7 = __builtin_amdgcn_mfma_i32_32x32x32_i8(a3, b4, acc7, 0, 0, 0);
    }
    __syncthreads();
  }

  // ---- f64 combine: logit = 2^-69 * (sum_s 2^(8s) acc_s + comp) ----
  double part[16];
  #pragma unroll
  for (int r = 0; r < 16; ++r) {
    int ex = e2 * 32 + qcol[r];
    part[r] = (16777216.0              * (double)acc3[r]
             + 4294967296.0            * (double)acc4[r]
             + 1099511627776.0         * (double)acc5[r]
             + 281474976710656.0       * (double)acc6[r]
             + 72057594037927936.0     * (double)acc7[r]
             + compT[kh * 64 + ex]) * 1.6940658945086007e-21;
  }
  if (kh == 0) {
    #pragma unroll
    for (int r = 0; r < 16; ++r)
      Ls[qrow[r] * E + e2 * 32 + qcol[r]] = part[r];
  }
  __syncthreads();
  #pragma unroll
  for (int g = 1; g < 4; ++g) {
    if (kh == g) {
      #pragma unroll
      for (int r = 0; r < 16; ++r)
        Ls[qrow[r] * E + e2 * 32 + qcol[r]] += part[r];
    }
    __syncthreads();
  }

  // ---- per-token softmax + top-8 on f64 logits (verified R2/R4-R7) ----
  for (int tt = 0; tt < 4; tt++) {
    int t = w * 4 + tt;
    double val = Ls[t * E + lane];

    double mx = val;
    #pragma unroll
    for (int off = 32; off >= 1; off >>= 1)
      mx = fmax(mx, __shfl_xor(mx, off));

    double p = exp(val - mx);
    double S = p;
    #pragma unroll
    for (int off = 32; off >= 1; off >>= 1)
      S += __shfl_xor(S, off);

    double cur = val;
    double myw = 0.0; int myidx = 0;
    double psum = 0.0;
    #pragma unroll
    for (int r = 0; r < TOPK; r++) {
      double v = cur; int ii = lane;
      #pragma unroll
      for (int off = 32; off >= 1; off >>= 1) {
        double ov = __shfl_xor(v, off);
        int    oi = __shfl_xor(ii, off);
        if (ov > v || (ov == v && oi < ii)) { v = ov; ii = oi; }
      }
      double pw = __shfl(p, ii);
      psum += pw;
      if (lane == r) { myw = pw; myidx = ii; }
      if (lane == ii) cur = -INFINITY;
    }
    double denom = psum / S + 1e-20;
    if (lane < TOPK) {
      size_t gt = (size_t)(t0 + t);
      out[gt * TOPK + lane] = (float)((myw / S) / denom);
      out[(size_t)n_tokens * TOPK + gt * TOPK + lane] = (float)myidx;
    }
  }
}

extern "C" void kernel_launch(void* const* d_in, const int* in_sizes, int n_in,
                              void* d_out, int out_size, void* d_ws, size_t ws_size,
                              hipStream_t stream)
{
  const float* X  = (const float*)d_in[0];
  const float* Wg = (const float*)d_in[1];
  float* out = (float*)d_out;
  signed char* Wb = (signed char*)d_ws;                 // 1.25 MB limb planes
  double* compT   = (double*)((char*)d_ws + 1310720);   // 2 KB comp table
  int n_tokens = in_sizes[0] / H;                        // 16384

  prep_w<<<64, 256, 0, stream>>>(Wg, Wb);
  comp_w<<<1, 256, 0, stream>>>(Wg, compT);
  moe_gate_i8<<<n_tokens / TILE_T, 512, 0, stream>>>(X, Wb, compT, out, n_tokens);
}

// Round 9
// 151.961 us; speedup vs baseline: 1.8443x; 1.8443x over previous
//
#include <hip/hip_runtime.h>
#include <math.h>

typedef float  f32x4  __attribute__((ext_vector_type(4)));
typedef int    i32x4  __attribute__((ext_vector_type(4)));
typedef int    i32x16 __attribute__((ext_vector_type(16)));

#define H      4096
#define E      64
#define TOPK   8
#define TILE_T 32

// W -> 5 balanced i8 limbs of round(w*2^41), MFMA-B-fragment order (R8-proven):
// Wb[((m*2+e2)*5 + j)*1024 + lane*16 + slot], lane=(h<<5)|(e&31), k=32m+16h+slot
__global__ __launch_bounds__(256)
void prep_w(const float* __restrict__ Wg, signed char* __restrict__ Wb)
{
  int n = blockIdx.x * 256 + threadIdx.x;   // 16384 = e(64) x m(128) x h(2)
  int h = n & 1, m = (n >> 1) & 127, e = n >> 8;
  const float* wp = Wg + e * 4096 + m * 32 + h * 16;
  signed char lb[5][16];
  #pragma unroll
  for (int s = 0; s < 16; ++s) {
    long long v = (long long)rint((double)wp[s] * 2199023255552.0); // 2^41
    #pragma unroll
    for (int j = 0; j < 4; ++j) {
      signed char b = (signed char)(v & 0xff);
      lb[j][s] = b;
      v = (v - b) >> 8;
    }
    lb[4][s] = (signed char)v;
  }
  int lanei = (h << 5) | (e & 31);
  int e2 = e >> 5;
  #pragma unroll
  for (int j = 0; j < 5; ++j) {
    i32x4 d;
    #pragma unroll
    for (int r = 0; r < 4; ++r)
      d[r] = (lb[j][4*r] & 0xFF) | ((lb[j][4*r+1] & 0xFF) << 8)
           | ((lb[j][4*r+2] & 0xFF) << 16) | ((lb[j][4*r+3] & 0xFF) << 24);
    *(i32x4*)(Wb + (((size_t)(m * 2 + e2) * 5 + j) << 10) + lanei * 16) = d;
  }
}

// comp[kH][e] = C0 * sum_{k in K-half} round(w*2^41). Integer sums are exact
// in f64 -> order-free. Parallel: 128 blocks (R8's 1-block version was ~50us).
__global__ __launch_bounds__(64)
void comp_w(const float* __restrict__ Wg, double* __restrict__ compT)
{
  int b = blockIdx.x;            // 128 = kH(2) x e(64)
  int kH = b >> 6, e = b & 63;
  int lane = threadIdx.x;
  double s = 0.0;
  #pragma unroll 4
  for (int i = 0; i < 32; ++i)
    s += rint((double)Wg[e * 4096 + kH * 2048 + i * 64 + lane] * 2199023255552.0);
  #pragma unroll
  for (int off = 32; off >= 1; off >>= 1)
    s += __shfl_xor(s, off);
  if (lane == 0) compT[kH * 64 + e] = 8421504.0 * s;
}

// Router on the i8 pipe, R8-proven math, zero-LDS main loop: each lane
// converts its own A-fragment bytes in registers (v_perm gather). Wave =
// 32tok x 32exp x K-half; block = 4 waves (kH x e2); no barriers until the
// f64 combine. 2-deep A prefetch, 1-deep B prefetch, chain-round-robin MFMAs.
__global__ __launch_bounds__(256, 2)
void moe_gate_i8(const float* __restrict__ X, const signed char* __restrict__ Wb,
                 const double* __restrict__ compT, float* __restrict__ out,
                 int n_tokens)
{
  __shared__ double Ls[TILE_T * E];   // 16 KB

  const int tid  = threadIdx.x;
  const int lane = tid & 63;
  const int w    = tid >> 6;     // 0..3
  const int kH   = w >> 1;       // K half
  const int e2   = w & 1;        // expert half
  const int t0   = blockIdx.x * TILE_T;
  const int l31  = lane & 31;
  const int h    = lane >> 5;

  // ---- probe (lane,reg)->(row,col) readout (R8-proven) ----
  i32x16 z;
  #pragma unroll
  for (int r = 0; r < 16; ++r) z[r] = 0;
  int lab = l31 * 0x01010101;
  i32x4 onev = {0x01010101, 0x01010101, 0x01010101, 0x01010101};
  i32x4 labv = {lab, lab, lab, lab};
  i32x16 pr = __builtin_amdgcn_mfma_i32_32x32x32_i8(labv, onev, z, 0, 0, 0);
  i32x16 pc = __builtin_amdgcn_mfma_i32_32x32x32_i8(onev, labv, z, 0, 0, 0);
  int qrow[16], qcol[16];
  #pragma unroll
  for (int r = 0; r < 16; ++r) { qrow[r] = pr[r] >> 5; qcol[r] = pc[r] >> 5; }

  i32x16 acc3 = z, acc4 = z, acc5 = z, acc6 = z, acc7 = z;

  // lane (h,l31): A-frag = token t0+l31, k = kH*2048 + m*32 + 16h + slot
  const float* ap = X + (size_t)(t0 + l31) * H + kH * 2048 + h * 16;
  const signed char* bp = Wb + (((size_t)(kH * 64) * 2 + e2) * 5 << 10) + lane * 16;

  f32x4 arA[4], arB[4];          // 2-deep A prefetch (named, static indexing)
  #pragma unroll
  for (int q = 0; q < 4; ++q) {
    arA[q] = *(const f32x4*)(ap + 0 * 32 + 4 * q);
    arB[q] = *(const f32x4*)(ap + 1 * 32 + 4 * q);
  }
  i32x4 bcur[5];
  #pragma unroll
  for (int j = 0; j < 5; ++j)
    bcur[j] = *(const i32x4*)(bp + (j << 10));

  // one 32-k step: convert abuf -> 4 limb planes, prefetch, 14 MFMAs
  #define STEP(abuf, MM)                                                      \
  {                                                                           \
    const int m_ = (MM);                                                      \
    unsigned w32[16];                                                         \
    _Pragma("unroll")                                                         \
    for (int q = 0; q < 4; ++q) {                                             \
      f32x4 xv = abuf[q];                                                     \
      _Pragma("unroll")                                                       \
      for (int jj = 0; jj < 4; ++jj)                                          \
        w32[q*4+jj] = ((unsigned)(int)(xv[jj] * 268435456.0f)) ^ 0x00808080u; \
    }                                                                         \
    if (m_ < 62) {                                                            \
      _Pragma("unroll")                                                       \
      for (int q = 0; q < 4; ++q)                                             \
        abuf[q] = *(const f32x4*)(ap + (m_ + 2) * 32 + 4 * q);                \
    }                                                                         \
    i32x4 bnxt[5];                                                            \
    if (m_ < 63) {                                                            \
      _Pragma("unroll")                                                       \
      for (int j = 0; j < 5; ++j)                                             \
        bnxt[j] = *(const i32x4*)(bp + (size_t)(m_ + 1) * 10240 + (j << 10)); \
    }                                                                         \
    i32x4 a0, a1, a2, a3;                                                     \
    _Pragma("unroll")                                                         \
    for (int r = 0; r < 4; ++r) {                                             \
      unsigned u0 = w32[4*r], u1 = w32[4*r+1], u2 = w32[4*r+2], u3 = w32[4*r+3];\
      unsigned p01, p23;                                                      \
      p01 = __builtin_amdgcn_perm(u1, u0, 0x04000400u);                       \
      p23 = __builtin_amdgcn_perm(u3, u2, 0x04000400u);                       \
      a0[r] = (int)__builtin_amdgcn_perm(p23, p01, 0x05040100u);              \
      p01 = __builtin_amdgcn_perm(u1, u0, 0x05010501u);                       \
      p23 = __builtin_amdgcn_perm(u3, u2, 0x05010501u);                       \
      a1[r] = (int)__builtin_amdgcn_perm(p23, p01, 0x05040100u);              \
      p01 = __builtin_amdgcn_perm(u1, u0, 0x06020602u);                       \
      p23 = __builtin_amdgcn_perm(u3, u2, 0x06020602u);                       \
      a2[r] = (int)__builtin_amdgcn_perm(p23, p01, 0x05040100u);              \
      p01 = __builtin_amdgcn_perm(u1, u0, 0x07030703u);                       \
      p23 = __builtin_amdgcn_perm(u3, u2, 0x07030703u);                       \
      a3[r] = (int)__builtin_amdgcn_perm(p23, p01, 0x05040100u);              \
    }                                                                         \
    acc3 = __builtin_amdgcn_mfma_i32_32x32x32_i8(a0, bcur[3], acc3, 0, 0, 0); \
    acc4 = __builtin_amdgcn_mfma_i32_32x32x32_i8(a0, bcur[4], acc4, 0, 0, 0); \
    acc5 = __builtin_amdgcn_mfma_i32_32x32x32_i8(a1, bcur[4], acc5, 0, 0, 0); \
    acc6 = __builtin_amdgcn_mfma_i32_32x32x32_i8(a2, bcur[4], acc6, 0, 0, 0); \
    acc7 = __builtin_amdgcn_mfma_i32_32x32x32_i8(a3, bcur[4], acc7, 0, 0, 0); \
    acc3 = __builtin_amdgcn_mfma_i32_32x32x32_i8(a1, bcur[2], acc3, 0, 0, 0); \
    acc4 = __builtin_amdgcn_mfma_i32_32x32x32_i8(a1, bcur[3], acc4, 0, 0, 0); \
    acc5 = __builtin_amdgcn_mfma_i32_32x32x32_i8(a2, bcur[3], acc5, 0, 0, 0); \
    acc6 = __builtin_amdgcn_mfma_i32_32x32x32_i8(a3, bcur[3], acc6, 0, 0, 0); \
    acc3 = __builtin_amdgcn_mfma_i32_32x32x32_i8(a2, bcur[1], acc3, 0, 0, 0); \
    acc4 = __builtin_amdgcn_mfma_i32_32x32x32_i8(a2, bcur[2], acc4, 0, 0, 0); \
    acc5 = __builtin_amdgcn_mfma_i32_32x32x32_i8(a3, bcur[2], acc5, 0, 0, 0); \
    acc3 = __builtin_amdgcn_mfma_i32_32x32x32_i8(a3, bcur[0], acc3, 0, 0, 0); \
    acc4 = __builtin_amdgcn_mfma_i32_32x32x32_i8(a3, bcur[1], acc4, 0, 0, 0); \
    if (m_ < 63) {                                                            \
      _Pragma("unroll")                                                       \
      for (int j = 0; j < 5; ++j) bcur[j] = bnxt[j];                          \
    }                                                                         \
  }

  for (int m2 = 0; m2 < 32; ++m2) {
    STEP(arA, 2 * m2);
    STEP(arB, 2 * m2 + 1);
  }
  #undef STEP

  // ---- f64 combine (exact scales; kH0 writes, kH1 adds) ----
  double part[16];
  #pragma unroll
  for (int r = 0; r < 16; ++r) {
    int ex = e2 * 32 + qcol[r];
    part[r] = (16777216.0              * (double)acc3[r]
             + 4294967296.0            * (double)acc4[r]
             + 1099511627776.0         * (double)acc5[r]
             + 281474976710656.0       * (double)acc6[r]
             + 72057594037927936.0     * (double)acc7[r]
             + compT[kH * 64 + ex]) * 1.6940658945086007e-21;
  }
  if (kH == 0) {
    #pragma unroll
    for (int r = 0; r < 16; ++r)
      Ls[qrow[r] * E + e2 * 32 + qcol[r]] = part[r];
  }
  __syncthreads();
  if (kH == 1) {
    #pragma unroll
    for (int r = 0; r < 16; ++r)
      Ls[qrow[r] * E + e2 * 32 + qcol[r]] += part[r];
  }
  __syncthreads();

  // ---- per-token softmax + top-8 on f64 logits (R2/R4-R8-proven) ----
  for (int tt = 0; tt < 8; tt++) {
    int t = w * 8 + tt;
    double val = Ls[t * E + lane];

    double mx = val;
    #pragma unroll
    for (int off = 32; off >= 1; off >>= 1)
      mx = fmax(mx, __shfl_xor(mx, off));

    double p = exp(val - mx);
    double S = p;
    #pragma unroll
    for (int off = 32; off >= 1; off >>= 1)
      S += __shfl_xor(S, off);

    double cur = val;
    double myw = 0.0; int myidx = 0;
    double psum = 0.0;
    #pragma unroll
    for (int r = 0; r < TOPK; r++) {
      double v = cur; int ii = lane;
      #pragma unroll
      for (int off = 32; off >= 1; off >>= 1) {
        double ov = __shfl_xor(v, off);
        int    oi = __shfl_xor(ii, off);
        if (ov > v || (ov == v && oi < ii)) { v = ov; ii = oi; }
      }
      double pw = __shfl(p, ii);
      psum += pw;
      if (lane == r) { myw = pw; myidx = ii; }
      if (lane == ii) cur = -INFINITY;
    }
    double denom = psum / S + 1e-20;
    if (lane < TOPK) {
      size_t gt = (size_t)(t0 + t);
      out[gt * TOPK + lane] = (float)((myw / S) / denom);
      out[(size_t)n_tokens * TOPK + gt * TOPK + lane] = (float)myidx;
    }
  }
}

extern "C" void kernel_launch(void* const* d_in, const int* in_sizes, int n_in,
                              void* d_out, int out_size, void* d_ws, size_t ws_size,
                              hipStream_t stream)
{
  const float* X  = (const float*)d_in[0];
  const float* Wg = (const float*)d_in[1];
  float* out = (float*)d_out;
  signed char* Wb = (signed char*)d_ws;                 // 1.25 MB limb planes
  double* compT   = (double*)((char*)d_ws + 1310720);   // 1 KB comp table
  int n_tokens = in_sizes[0] / H;                        // 16384

  prep_w<<<64, 256, 0, stream>>>(Wg, Wb);
  comp_w<<<128, 64, 0, stream>>>(Wg, compT);
  moe_gate_i8<<<n_tokens / TILE_T, 256, 0, stream>>>(X, Wb, compT, out, n_tokens);
}